// Round 3
// baseline (1366.985 us; speedup 1.0000x reference)
//
#include <hip/hip_runtime.h>
#include <hip/hip_fp16.h>

#define NSEQ 8192
#define DIM  512

typedef _Float16 f16;
typedef _Float16 f16x8 __attribute__((ext_vector_type(8)));
typedef _Float16 f16x4 __attribute__((ext_vector_type(4)));
typedef float    f32x4 __attribute__((ext_vector_type(4)));

// ---------------------------------------------------------------------------
// Kernel 0a: C = X(8192x512) * W(512x512) in fp32 (vector ALU), epilogue
// splits each fp32 value into f16 hi + f16 lo. scale folds 1/sqrt(512) into Q.
// ---------------------------------------------------------------------------
__global__ __launch_bounds__(256) void k_proj_split(
    const float* __restrict__ X, const float* __restrict__ W,
    f16* __restrict__ Oh, f16* __restrict__ Ol, float scale)
{
  __shared__ float As[16][68];
  __shared__ float Bs[16][64];
  const int tid = threadIdx.x;
  const int r0 = blockIdx.x * 64;
  const int c0 = blockIdx.y * 64;
  const int tx = tid & 15, ty = tid >> 4;
  float acc[4][4] = {};
  for (int k0 = 0; k0 < DIM; k0 += 16) {
#pragma unroll
    for (int e = 0; e < 4; ++e) {
      int idx = tid + e * 256;
      As[idx & 15][idx >> 4] = X[(size_t)(r0 + (idx >> 4)) * DIM + k0 + (idx & 15)];
    }
#pragma unroll
    for (int e = 0; e < 4; ++e) {
      int idx = tid + e * 256;
      Bs[idx >> 6][idx & 63] = W[(size_t)(k0 + (idx >> 6)) * DIM + c0 + (idx & 63)];
    }
    __syncthreads();
#pragma unroll
    for (int kk = 0; kk < 16; ++kk) {
      f32x4 a = *(const f32x4*)&As[kk][ty * 4];
      f32x4 b = *(const f32x4*)&Bs[kk][tx * 4];
#pragma unroll
      for (int i = 0; i < 4; ++i)
#pragma unroll
        for (int j = 0; j < 4; ++j)
          acc[i][j] = fmaf(a[i], b[j], acc[i][j]);
    }
    __syncthreads();
  }
#pragma unroll
  for (int i = 0; i < 4; ++i) {
    f16x4 hv, lv;
#pragma unroll
    for (int j = 0; j < 4; ++j) {
      float c = acc[i][j] * scale;
      f16 h = (f16)c;
      hv[j] = h;
      lv[j] = (f16)(c - (float)h);
    }
    size_t addr = (size_t)(r0 + ty * 4 + i) * DIM + c0 + tx * 4;
    *(f16x4*)&Oh[addr] = hv;
    *(f16x4*)&Ol[addr] = lv;
  }
}

// ---------------------------------------------------------------------------
// Kernel 0b: XhT[d][j] = f16(X[j][d])   (V in [d][j] layout for PV A-operand)
// ---------------------------------------------------------------------------
__global__ __launch_bounds__(256) void k_xt(const float* __restrict__ X,
                                            f16* __restrict__ XhT)
{
  __shared__ float T[64][65];
  const int tid = threadIdx.x;
  const int j0 = blockIdx.x * 64;
  const int d0 = blockIdx.y * 64;
#pragma unroll
  for (int e = 0; e < 16; ++e) {
    int idx = tid + e * 256;
    T[idx >> 6][idx & 63] = X[(size_t)(j0 + (idx >> 6)) * DIM + d0 + (idx & 63)];
  }
  __syncthreads();
#pragma unroll
  for (int e = 0; e < 16; ++e) {
    int idx = tid + e * 256;
    int dd = idx >> 6, jj = idx & 63;
    XhT[(size_t)(d0 + dd) * NSEQ + j0 + jj] = (f16)T[jj][dd];
  }
}

// ---------------------------------------------------------------------------
// FUSED flash attention. One block = 8 waves = 512 threads, Q-tile 128 rows,
// KV-slice = NSEQ/Z handled in nt tiles of KVB=128.
// Phase 1: S^T[j][q] = K·Q^T, split-f16 (3 MFMA), d-chunks of 64 staged in LDS.
// Phase 2: online softmax (C-cols = q so row-reduce = 2 shfl + LDS[128][2]).
// Phase 3: O^T[d][q] += V·P^T, V = XhT rows staged per 64-d step (time-shares
//          the 64KB QK LDS region), P f16 in 32KB LDS.
// Outputs unnormalized O^T partial (stored [q][d]) + running m,l per q.
// ---------------------------------------------------------------------------
__global__ __launch_bounds__(512, 2) void k_flash(
    const f16* __restrict__ Qh, const f16* __restrict__ Ql,
    const f16* __restrict__ Kh, const f16* __restrict__ Kl,
    const f16* __restrict__ XhT,
    float* __restrict__ Opart, float* __restrict__ mpart,
    float* __restrict__ lpart, int nt)
{
  __shared__ __align__(16) char lds[101888];
  char* QKV = lds;                 // 64 KB: QK chunks (4x16KB) / V stage
  char* Pl  = lds + 65536;         // 32 KB: P^T tile [128 q][128 j] f16
  float* m_l  = (float*)(lds + 98304);   // [128]
  float* l_l  = m_l + 128;               // [128]
  float* resc = m_l + 256;               // [128]
  float* redm = m_l + 384;               // [128][2]
  float* reds = m_l + 640;               // [128][2]

  const int tid  = threadIdx.x;
  const int lane = tid & 63;
  const int w    = tid >> 6;
  const int frow = lane & 15;
  const int lhi  = lane >> 4;            // 0..3
  // QK^T wave grid: jw in {0,1} (j 64-range), qw in {0..3} (q 32-range)
  const int jw = w >> 2, qw = w & 3;
  // PV wave grid: qw2 in {0,1} (q 64-range), dw in {0..3} (d 128-range)
  const int qw2 = w >> 2, dw = w & 3;

  const int qb = blockIdx.x * 128;
  const int z  = blockIdx.y;
  const int j0base = z * nt * 128;

  // ---- staging geometry ----
  // QK: 8 x 16B per thread; g -> matrix (g>>1), row (0..127), k16 (0..7)
  int srow[8], slds[8];
#pragma unroll
  for (int g = 0; g < 8; ++g) {
    int idx = (g & 1) * 512 + tid;
    int row = idx >> 3, k16 = idx & 7;
    srow[g] = row;
    slds[g] = (g >> 1) * 16384 + ((row * 128 + k16 * 16) ^ ((row & 7) << 4));
  }
  const int sk8 = (tid & 7) * 8;         // k16*8 f16 elems
  // V: 2 threads/row: vrow 0..255, vhalf 0..1; 8 x 16B each
  const int vrow = tid >> 1, vhalf = tid & 1;
  int vlds[8];
#pragma unroll
  for (int cc = 0; cc < 8; ++cc)
    vlds[cc] = vrow * 256 + ((vhalf * 128 + cc * 16) ^ ((vrow & 7) << 4));

  uint4 pre[8];

  // ---- init ----
  if (tid < 128) { m_l[tid] = -3.0e38f; l_l[tid] = 0.f; }
  f32x4 accO0[4][4] = {};   // s=0: d = dw*128 +      m2*16+..., q = qw2*64 + n2*16+...
  f32x4 accO1[4][4] = {};   // s=1: d = dw*128 + 64 + ...

  // prologue: prefetch QK chunk 0 of tile 0
#pragma unroll
  for (int g = 0; g < 8; ++g) {
    const f16* bp = (g < 2) ? Qh : (g < 4) ? Ql : (g < 6) ? Kh : Kl;
    int rb = (g < 4) ? qb : j0base;
    pre[g] = *(const uint4*)(bp + (size_t)(rb + srow[g]) * DIM + sk8);
  }

  for (int t = 0; t < nt; ++t) {
    const int j0t = j0base + t * 128;
    f32x4 accS[4][2] = {};

    // ---------------- Phase 1: S^T = K . Q^T over 8 d-chunks ----------------
#pragma unroll
    for (int c = 0; c < 8; ++c) {
      __syncthreads();                    // LDS region free
#pragma unroll
      for (int g = 0; g < 8; ++g) *(uint4*)(QKV + slds[g]) = pre[g];
      __syncthreads();                    // chunk visible
      if (c < 7) {
        const int d0 = (c + 1) * 64;
#pragma unroll
        for (int g = 0; g < 8; ++g) {
          const f16* bp = (g < 2) ? Qh : (g < 4) ? Ql : (g < 6) ? Kh : Kl;
          int rb = (g < 4) ? qb : j0t;
          pre[g] = *(const uint4*)(bp + (size_t)(rb + srow[g]) * DIM + d0 + sk8);
        }
      } else {
        // prefetch V s=0 rows
        const int gd = (vrow >> 6) * 128 + (vrow & 63);
        const f16* bp = XhT + (size_t)gd * NSEQ + j0t + vhalf * 64;
#pragma unroll
        for (int cc = 0; cc < 8; ++cc) pre[cc] = *(const uint4*)(bp + cc * 8);
      }
      // MFMA on chunk c
#pragma unroll
      for (int kk = 0; kk < 2; ++kk) {
        const int kb = kk * 64 + lhi * 16;
        f16x8 ah[4], al[4], bh[2], bl[2];
#pragma unroll
        for (int m = 0; m < 4; ++m) {
          const int jr = jw * 64 + m * 16 + frow;
          const int off = jr * 128 + (kb ^ ((jr & 7) << 4));
          ah[m] = *(const f16x8*)(QKV + 32768 + off);
          al[m] = *(const f16x8*)(QKV + 49152 + off);
        }
#pragma unroll
        for (int n = 0; n < 2; ++n) {
          const int qr = qw * 32 + n * 16 + frow;
          const int off = qr * 128 + (kb ^ ((qr & 7) << 4));
          bh[n] = *(const f16x8*)(QKV + off);
          bl[n] = *(const f16x8*)(QKV + 16384 + off);
        }
#pragma unroll
        for (int m = 0; m < 4; ++m)
#pragma unroll
          for (int n = 0; n < 2; ++n) {
            accS[m][n] = __builtin_amdgcn_mfma_f32_16x16x32_f16(ah[m], bh[n], accS[m][n], 0, 0, 0);
            accS[m][n] = __builtin_amdgcn_mfma_f32_16x16x32_f16(ah[m], bl[n], accS[m][n], 0, 0, 0);
            accS[m][n] = __builtin_amdgcn_mfma_f32_16x16x32_f16(al[m], bh[n], accS[m][n], 0, 0, 0);
          }
      }
    }

    // ---------------- Phase 2: online softmax ----------------
    float cmax[2];
#pragma unroll
    for (int n = 0; n < 2; ++n) {
      float cm = -3.0e38f;
#pragma unroll
      for (int m = 0; m < 4; ++m)
#pragma unroll
        for (int r = 0; r < 4; ++r) cm = fmaxf(cm, accS[m][n][r]);
      cm = fmaxf(cm, __shfl_xor(cm, 16));
      cm = fmaxf(cm, __shfl_xor(cm, 32));
      cmax[n] = cm;
    }
    if (lane < 16) {
      redm[(qw * 32 + lane) * 2 + jw]      = cmax[0];
      redm[(qw * 32 + 16 + lane) * 2 + jw] = cmax[1];
    }
    __syncthreads();
    if (tid < 128) {
      float tm = fmaxf(redm[tid * 2], redm[tid * 2 + 1]);
      float mo = m_l[tid];
      float mn = fmaxf(mo, tm);
      m_l[tid] = mn;
      resc[tid] = __expf(mo - mn);
    }
    __syncthreads();
    // P = exp(S - m), write P^T to LDS, column sums
    float csum[2];
#pragma unroll
    for (int n = 0; n < 2; ++n) {
      const int q = qw * 32 + n * 16 + frow;
      const float mq = m_l[q];
      float cs = 0.f;
#pragma unroll
      for (int m = 0; m < 4; ++m) {
        f16x4 pv;
#pragma unroll
        for (int r = 0; r < 4; ++r) {
          float p = __expf(accS[m][n][r] - mq);
          cs += p;
          pv[r] = (f16)p;
        }
        *(f16x4*)(Pl + ((q * 256 + (jw * 64 + m * 16 + lhi * 4) * 2) ^ ((q & 7) << 4))) = pv;
      }
      cs += __shfl_xor(cs, 16);
      cs += __shfl_xor(cs, 32);
      csum[n] = cs;
    }
    if (lane < 16) {
      reds[(qw * 32 + lane) * 2 + jw]      = csum[0];
      reds[(qw * 32 + 16 + lane) * 2 + jw] = csum[1];
    }
    // rescale O accumulators
    {
      float rs[4];
#pragma unroll
      for (int n2 = 0; n2 < 4; ++n2) rs[n2] = resc[qw2 * 64 + n2 * 16 + frow];
#pragma unroll
      for (int m2 = 0; m2 < 4; ++m2)
#pragma unroll
        for (int n2 = 0; n2 < 4; ++n2) {
          accO0[m2][n2] *= rs[n2];
          accO1[m2][n2] *= rs[n2];
        }
    }
    __syncthreads();                      // P_lds + reds ready; QK region free
    if (tid < 128)
      l_l[tid] = l_l[tid] * resc[tid] + reds[tid * 2] + reds[tid * 2 + 1];

    // ---------------- Phase 3: O^T += V . P^T ----------------
    // V s=0 (already in pre) -> LDS
#pragma unroll
    for (int cc = 0; cc < 8; ++cc) *(uint4*)(QKV + vlds[cc]) = pre[cc];
    // prefetch V s=1
    {
      const int gd = (vrow >> 6) * 128 + 64 + (vrow & 63);
      const f16* bp = XhT + (size_t)gd * NSEQ + j0t + vhalf * 64;
#pragma unroll
      for (int cc = 0; cc < 8; ++cc) pre[cc] = *(const uint4*)(bp + cc * 8);
    }
    __syncthreads();
#pragma unroll
    for (int kk = 0; kk < 4; ++kk) {
      const int kb = kk * 64 + lhi * 16;
      f16x8 va[4], pb[4];
#pragma unroll
      for (int m2 = 0; m2 < 4; ++m2) {
        const int dr = dw * 64 + m2 * 16 + frow;
        va[m2] = *(const f16x8*)(QKV + dr * 256 + (kb ^ ((dr & 7) << 4)));
      }
#pragma unroll
      for (int n2 = 0; n2 < 4; ++n2) {
        const int q = qw2 * 64 + n2 * 16 + frow;
        pb[n2] = *(const f16x8*)(Pl + q * 256 + (kb ^ ((q & 7) << 4)));
      }
#pragma unroll
      for (int m2 = 0; m2 < 4; ++m2)
#pragma unroll
        for (int n2 = 0; n2 < 4; ++n2)
          accO0[m2][n2] = __builtin_amdgcn_mfma_f32_16x16x32_f16(va[m2], pb[n2], accO0[m2][n2], 0, 0, 0);
    }
    __syncthreads();                      // V region free
#pragma unroll
    for (int cc = 0; cc < 8; ++cc) *(uint4*)(QKV + vlds[cc]) = pre[cc];
    if (t + 1 < nt) {
      // prefetch QK chunk 0 of next tile
#pragma unroll
      for (int g = 0; g < 8; ++g) {
        const f16* bp = (g < 2) ? Qh : (g < 4) ? Ql : (g < 6) ? Kh : Kl;
        int rb = (g < 4) ? qb : (j0t + 128);
        pre[g] = *(const uint4*)(bp + (size_t)(rb + srow[g]) * DIM + sk8);
      }
    }
    __syncthreads();
#pragma unroll
    for (int kk = 0; kk < 4; ++kk) {
      const int kb = kk * 64 + lhi * 16;
      f16x8 va[4], pb[4];
#pragma unroll
      for (int m2 = 0; m2 < 4; ++m2) {
        const int dr = dw * 64 + m2 * 16 + frow;
        va[m2] = *(const f16x8*)(QKV + dr * 256 + (kb ^ ((dr & 7) << 4)));
      }
#pragma unroll
      for (int n2 = 0; n2 < 4; ++n2) {
        const int q = qw2 * 64 + n2 * 16 + frow;
        pb[n2] = *(const f16x8*)(Pl + q * 256 + (kb ^ ((q & 7) << 4)));
      }
#pragma unroll
      for (int m2 = 0; m2 < 4; ++m2)
#pragma unroll
        for (int n2 = 0; n2 < 4; ++n2)
          accO1[m2][n2] = __builtin_amdgcn_mfma_f32_16x16x32_f16(va[m2], pb[n2], accO1[m2][n2], 0, 0, 0);
    }
  }

  // ---------------- epilogue: unnormalized partial O, m, l ----------------
  float* op = Opart + (size_t)z * NSEQ * DIM;
#pragma unroll
  for (int n2 = 0; n2 < 4; ++n2) {
    const int qg = qb + qw2 * 64 + n2 * 16 + frow;
#pragma unroll
    for (int m2 = 0; m2 < 4; ++m2) {
      const int d0 = dw * 128 + m2 * 16 + lhi * 4;
#pragma unroll
      for (int r = 0; r < 4; ++r) {
        op[(size_t)qg * DIM + d0 + r]      = accO0[m2][n2][r];
        op[(size_t)qg * DIM + d0 + 64 + r] = accO1[m2][n2][r];
      }
    }
  }
  if (tid < 128) {
    mpart[z * NSEQ + qb + tid] = m_l[tid];
    lpart[z * NSEQ + qb + tid] = l_l[tid];
  }
}

// ---------------------------------------------------------------------------
// Combine: Out[q][d] = sum_z e^{m_z-m_g} O_z[q][d] / sum_z e^{m_z-m_g} l_z
// Works in place when Opart == Out (Z == 1).
// ---------------------------------------------------------------------------
__global__ __launch_bounds__(256) void k_comb(
    const float* __restrict__ Opart, const float* __restrict__ mpart,
    const float* __restrict__ lpart, float* __restrict__ Out, int Z)
{
  const int idx = blockIdx.x * 256 + threadIdx.x;
  const int q = idx >> 7;
  const int d4 = idx & 127;
  float mg = -3.0e38f;
  for (int zz = 0; zz < Z; ++zz) mg = fmaxf(mg, mpart[zz * NSEQ + q]);
  f32x4 num = {0.f, 0.f, 0.f, 0.f};
  float den = 0.f;
  for (int zz = 0; zz < Z; ++zz) {
    float wz = __expf(mpart[zz * NSEQ + q] - mg);
    den += wz * lpart[zz * NSEQ + q];
    f32x4 v = *(const f32x4*)(Opart + (size_t)zz * NSEQ * DIM + (size_t)q * DIM + d4 * 4);
    num += v * wz;
  }
  num *= (1.0f / den);
  *(f32x4*)(Out + (size_t)q * DIM + d4 * 4) = num;
}

// ---------------------------------------------------------------------------
extern "C" void kernel_launch(void* const* d_in, const int* in_sizes, int n_in,
                              void* d_out, int out_size, void* d_ws, size_t ws_size,
                              hipStream_t stream) {
  const float* Wq = (const float*)d_in[0];
  const float* Wk = (const float*)d_in[1];
  const float* X  = (const float*)d_in[2];
  float* Out = (float*)d_out;

  char* w = (char*)d_ws;
  const size_t SPLIT = (size_t)NSEQ * DIM * 2;      // 8 MB per f16 matrix
  f16* Qh  = (f16*)(w);
  f16* Ql  = (f16*)(w + SPLIT);
  f16* Kh  = (f16*)(w + 2 * SPLIT);
  f16* Kl  = (f16*)(w + 3 * SPLIT);
  f16* XhT = (f16*)(w + 4 * SPLIT);
  float* mpart = (float*)(w + 5 * SPLIT);           // up to 8 * 32 KB
  float* lpart = (float*)(w + 5 * SPLIT + 262144);
  char* rest = w + 5 * SPLIT + 524288;
  const size_t used_base = 5 * SPLIT + 524288;
  const size_t OPART1 = (size_t)NSEQ * DIM * 4;     // 16 MB per z-slice

  int Z;
  float* Opart;
  if (ws_size >= used_base + 4 * OPART1)      { Z = 4; Opart = (float*)rest; }
  else if (ws_size >= used_base + 2 * OPART1) { Z = 2; Opart = (float*)rest; }
  else if (ws_size >= used_base + OPART1)     { Z = 1; Opart = (float*)rest; }
  else                                        { Z = 1; Opart = Out; }
  const int nt = NSEQ / (Z * 128);

  const float SCALE = 0.044194173824159216f;  // 1/sqrt(512)
  k_proj_split<<<dim3(NSEQ / 64, DIM / 64), 256, 0, stream>>>(X, Wq, Qh, Ql, SCALE);
  k_proj_split<<<dim3(NSEQ / 64, DIM / 64), 256, 0, stream>>>(X, Wk, Kh, Kl, 1.0f);
  k_xt<<<dim3(NSEQ / 64, DIM / 64), 256, 0, stream>>>(X, XhT);
  k_flash<<<dim3(NSEQ / 128, Z), 512, 0, stream>>>(Qh, Ql, Kh, Kl, XhT,
                                                   Opart, mpart, lpart, nt);
  k_comb<<<NSEQ * (DIM / 4) / 256, 256, 0, stream>>>(Opart, mpart, lpart, Out, Z);
}

// Round 4
// 740.035 us; speedup vs baseline: 1.8472x; 1.8472x over previous
//
#include <hip/hip_runtime.h>
#include <hip/hip_fp16.h>

#define NSEQ 8192
#define DIM  512
#define SPITCH 8256            // f32 elems per S row (NSEQ + 64, kills pow2 stride)
#define SROWB  33024           // bytes per S row
#define VPITCH 8256            // f16 elems per XhT row

typedef _Float16 f16;
typedef _Float16 f16x8 __attribute__((ext_vector_type(8)));
typedef _Float16 f16x4 __attribute__((ext_vector_type(4)));
typedef float    f32x4 __attribute__((ext_vector_type(4)));

// ---------------------------------------------------------------------------
// Kernel 0a: C = X(8192x512) * W(512x512) in fp32 (vector ALU), epilogue
// splits each fp32 value into f16 hi + f16 lo. scale folds 1/sqrt(512) into Q.
// ---------------------------------------------------------------------------
__global__ __launch_bounds__(256) void k_proj_split(
    const float* __restrict__ X, const float* __restrict__ W,
    f16* __restrict__ Oh, f16* __restrict__ Ol, float scale)
{
  __shared__ float As[16][68];
  __shared__ float Bs[16][64];
  const int tid = threadIdx.x;
  const int r0 = blockIdx.x * 64;
  const int c0 = blockIdx.y * 64;
  const int tx = tid & 15, ty = tid >> 4;
  float acc[4][4] = {};
  for (int k0 = 0; k0 < DIM; k0 += 16) {
#pragma unroll
    for (int e = 0; e < 4; ++e) {
      int idx = tid + e * 256;
      As[idx & 15][idx >> 4] = X[(size_t)(r0 + (idx >> 4)) * DIM + k0 + (idx & 15)];
    }
#pragma unroll
    for (int e = 0; e < 4; ++e) {
      int idx = tid + e * 256;
      Bs[idx >> 6][idx & 63] = W[(size_t)(k0 + (idx >> 6)) * DIM + c0 + (idx & 63)];
    }
    __syncthreads();
#pragma unroll
    for (int kk = 0; kk < 16; ++kk) {
      f32x4 a = *(const f32x4*)&As[kk][ty * 4];
      f32x4 b = *(const f32x4*)&Bs[kk][tx * 4];
#pragma unroll
      for (int i = 0; i < 4; ++i)
#pragma unroll
        for (int j = 0; j < 4; ++j)
          acc[i][j] = fmaf(a[i], b[j], acc[i][j]);
    }
    __syncthreads();
  }
#pragma unroll
  for (int i = 0; i < 4; ++i) {
    f16x4 hv, lv;
#pragma unroll
    for (int j = 0; j < 4; ++j) {
      float c = acc[i][j] * scale;
      f16 h = (f16)c;
      hv[j] = h;
      lv[j] = (f16)(c - (float)h);
    }
    size_t addr = (size_t)(r0 + ty * 4 + i) * DIM + c0 + tx * 4;
    *(f16x4*)&Oh[addr] = hv;
    *(f16x4*)&Ol[addr] = lv;
  }
}

// ---------------------------------------------------------------------------
// Kernel 0b: XhT[d][j] = f16(X[j][d])  (V in [d][j] layout, padded pitch)
// ---------------------------------------------------------------------------
__global__ __launch_bounds__(256) void k_xt(const float* __restrict__ X,
                                            f16* __restrict__ XhT)
{
  __shared__ float T[64][65];
  const int tid = threadIdx.x;
  const int j0 = blockIdx.x * 64;
  const int d0 = blockIdx.y * 64;
#pragma unroll
  for (int e = 0; e < 16; ++e) {
    int idx = tid + e * 256;
    T[idx >> 6][idx & 63] = X[(size_t)(j0 + (idx >> 6)) * DIM + d0 + (idx & 63)];
  }
  __syncthreads();
#pragma unroll
  for (int e = 0; e < 16; ++e) {
    int idx = tid + e * 256;
    int dd = idx >> 6, jj = idx & 63;
    XhT[(size_t)(d0 + dd) * VPITCH + j0 + jj] = (f16)T[jj][dd];
  }
}

// ---------------------------------------------------------------------------
// Pass A: S = Q K^T via split-f16 MFMA (3 mfma per fragment pair).
// 128x128 block tile, 4 waves (64x64 each), BK=32, XOR-swizzled LDS.
// S rows are chunk-local, pitch SPITCH.
// ---------------------------------------------------------------------------
__global__ __launch_bounds__(256) void k_qkt(
    const f16* __restrict__ Qh, const f16* __restrict__ Ql,
    const f16* __restrict__ Kh, const f16* __restrict__ Kl,
    float* __restrict__ S, int q0)
{
  __shared__ char sm[4 * 8192];   // Qh,Ql,Kh,Kl tiles: [128][32] f16, 8 KB each
  const int tid  = threadIdx.x;
  const int lane = tid & 63;
  const int w    = tid >> 6;
  const int wm   = (w >> 1) * 64;
  const int wn   = (w & 1) * 64;
  const int qrow0 = q0 + blockIdx.x * 128;
  const int krow0 = blockIdx.y * 128;

  const int r1 = tid >> 2;
  const int o1 = (tid & 3) * 8;
  const int sw1 = (r1 * 64 + (tid & 3) * 16) ^ ((r1 & 7) << 4);
  const int sw2 = ((r1 + 64) * 64 + (tid & 3) * 16) ^ (((r1 + 64) & 7) << 4);
  const f16* pQh = Qh + (size_t)(qrow0 + r1) * DIM + o1;
  const f16* pQl = Ql + (size_t)(qrow0 + r1) * DIM + o1;
  const f16* pKh = Kh + (size_t)(krow0 + r1) * DIM + o1;
  const f16* pKl = Kl + (size_t)(krow0 + r1) * DIM + o1;
  const int R64 = 64 * DIM;

  const int frow = lane & 15;
  const int fkb  = (lane >> 4) * 16;

  f32x4 acc[4][4] = {};

  for (int step = 0; step < 16; ++step) {
    const int d0 = step * 32;
    uint4 v0 = *(const uint4*)(pQh + d0);
    uint4 v1 = *(const uint4*)(pQh + R64 + d0);
    uint4 v2 = *(const uint4*)(pQl + d0);
    uint4 v3 = *(const uint4*)(pQl + R64 + d0);
    uint4 v4 = *(const uint4*)(pKh + d0);
    uint4 v5 = *(const uint4*)(pKh + R64 + d0);
    uint4 v6 = *(const uint4*)(pKl + d0);
    uint4 v7 = *(const uint4*)(pKl + R64 + d0);
    __syncthreads();
    *(uint4*)(sm +     0 + sw1) = v0;
    *(uint4*)(sm +     0 + sw2) = v1;
    *(uint4*)(sm +  8192 + sw1) = v2;
    *(uint4*)(sm +  8192 + sw2) = v3;
    *(uint4*)(sm + 16384 + sw1) = v4;
    *(uint4*)(sm + 16384 + sw2) = v5;
    *(uint4*)(sm + 24576 + sw1) = v6;
    *(uint4*)(sm + 24576 + sw2) = v7;
    __syncthreads();
    f16x8 aH[4], aL[4], bH[4], bL[4];
#pragma unroll
    for (int m = 0; m < 4; ++m) {
      int ra = wm + m * 16 + frow;
      int rb = wn + m * 16 + frow;
      int sa = (ra * 64 + fkb) ^ ((ra & 7) << 4);
      int sb = (rb * 64 + fkb) ^ ((rb & 7) << 4);
      aH[m] = *(const f16x8*)(sm +     0 + sa);
      aL[m] = *(const f16x8*)(sm +  8192 + sa);
      bH[m] = *(const f16x8*)(sm + 16384 + sb);
      bL[m] = *(const f16x8*)(sm + 24576 + sb);
    }
#pragma unroll
    for (int m = 0; m < 4; ++m)
#pragma unroll
      for (int n = 0; n < 4; ++n) {
        acc[m][n] = __builtin_amdgcn_mfma_f32_16x16x32_f16(aH[m], bH[n], acc[m][n], 0, 0, 0);
        acc[m][n] = __builtin_amdgcn_mfma_f32_16x16x32_f16(aH[m], bL[n], acc[m][n], 0, 0, 0);
        acc[m][n] = __builtin_amdgcn_mfma_f32_16x16x32_f16(aL[m], bH[n], acc[m][n], 0, 0, 0);
      }
  }

  const int srow0 = blockIdx.x * 128 + wm;   // chunk-local S row
  const int scol0 = krow0 + wn;
#pragma unroll
  for (int m = 0; m < 4; ++m)
#pragma unroll
    for (int n = 0; n < 4; ++n) {
      int row = srow0 + m * 16 + (lane >> 4) * 4;
      int col = scol0 + n * 16 + (lane & 15);
#pragma unroll
      for (int r = 0; r < 4; ++r)
        S[(size_t)(row + r) * SPITCH + col] = acc[m][n][r];
    }
}

// ---------------------------------------------------------------------------
// Pass B: one block per row. Row max + sum(exp), writes P=f16(exp(s-m)) and
// the row sum. P may overlay the S buffer (ppitch in f16 elems).
// ---------------------------------------------------------------------------
__global__ __launch_bounds__(256) void k_softmax(
    const float* __restrict__ S, f16* __restrict__ P,
    float* __restrict__ Lsum, int q0, int ppitch)
{
  __shared__ float red[4], red2[4];
  const int tid = threadIdx.x;
  const int r = blockIdx.x;
  const float* srow = S + (size_t)r * SPITCH;
  f32x4 v[8];
#pragma unroll
  for (int e = 0; e < 8; ++e)
    v[e] = *(const f32x4*)(srow + (size_t)(tid + e * 256) * 4);
  float m = -3.0e38f;
#pragma unroll
  for (int e = 0; e < 8; ++e)
#pragma unroll
    for (int i = 0; i < 4; ++i) m = fmaxf(m, v[e][i]);
#pragma unroll
  for (int off = 32; off; off >>= 1) m = fmaxf(m, __shfl_xor(m, off));
  if ((tid & 63) == 0) red[tid >> 6] = m;
  __syncthreads();
  m = fmaxf(fmaxf(red[0], red[1]), fmaxf(red[2], red[3]));
  float sum = 0.f;
#pragma unroll
  for (int e = 0; e < 8; ++e)
#pragma unroll
    for (int i = 0; i < 4; ++i) {
      float p = __expf(v[e][i] - m);
      v[e][i] = p;
      sum += p;
    }
#pragma unroll
  for (int off = 32; off; off >>= 1) sum += __shfl_xor(sum, off);
  if ((tid & 63) == 0) red2[tid >> 6] = sum;
  __syncthreads();
  sum = red2[0] + red2[1] + red2[2] + red2[3];
  if (tid == 0) Lsum[q0 + r] = sum;
  f16* prow = P + (size_t)(q0 + r) * ppitch;
#pragma unroll
  for (int e = 0; e < 8; ++e) {
    f16x4 p;
#pragma unroll
    for (int i = 0; i < 4; ++i) p[i] = (f16)v[e][i];
    *(f16x4*)(prow + (size_t)(tid + e * 256) * 4) = p;
  }
}

// ---------------------------------------------------------------------------
// Pass C (NEW): Opart^T = XhT * P^T, L2-direct, no LDS, no barriers.
// Block = 4 waves = 32 q x 512 d (waves split d -> V fragments read once per
// block; P fragments re-read 4x but L2-hot). Grid (NSEQ/32, Z); z-slice
// handles jrange = NSEQ/Z columns. Writes unscaled fp32 partial tile at
// obase + q*qstride + z*zstride + d*4.
// ---------------------------------------------------------------------------
__global__ __launch_bounds__(256, 4) void k_pv2(
    const f16* __restrict__ XhT, const f16* __restrict__ P,
    char* __restrict__ obase, int ppitch, size_t qstride, size_t zstride,
    int jrange)
{
  const int tid  = threadIdx.x;
  const int lane = tid & 63;
  const int w    = tid >> 6;
  const int frow = lane & 15;
  const int lhi  = lane >> 4;
  const int q0   = blockIdx.x * 32;
  const int z    = blockIdx.y;
  const int jbase = z * jrange;

  const f16* pa  = XhT + (size_t)(w * 128 + frow) * VPITCH + jbase + lhi * 8;
  const f16* pb0 = P + (size_t)(q0 + frow) * ppitch + jbase + lhi * 8;
  const f16* pb1 = pb0 + (size_t)16 * ppitch;

  f32x4 acc[8][2] = {};
  const int nsteps = jrange / 32;
  for (int s = 0; s < nsteps; ++s) {
    const int j = s * 32;
    f16x8 b0 = *(const f16x8*)(pb0 + j);
    f16x8 b1 = *(const f16x8*)(pb1 + j);
#pragma unroll
    for (int m2 = 0; m2 < 8; ++m2) {
      f16x8 a = *(const f16x8*)(pa + (size_t)(m2 * 16) * VPITCH + j);
      acc[m2][0] = __builtin_amdgcn_mfma_f32_16x16x32_f16(a, b0, acc[m2][0], 0, 0, 0);
      acc[m2][1] = __builtin_amdgcn_mfma_f32_16x16x32_f16(a, b1, acc[m2][1], 0, 0, 0);
    }
  }

  // C row = d = w*128 + m2*16 + lhi*4 + r ; C col = q = q0 + n2*16 + frow
#pragma unroll
  for (int m2 = 0; m2 < 8; ++m2)
#pragma unroll
    for (int n2 = 0; n2 < 2; ++n2) {
      const int qg = q0 + n2 * 16 + frow;
      char* p = obase + (size_t)qg * qstride + (size_t)z * zstride
                      + (size_t)(w * 128 + m2 * 16 + lhi * 4) * 4;
      *(f32x4*)p = acc[m2][n2];
    }
}

// ---------------------------------------------------------------------------
// Pass D: Out[q][d] = (sum_z Opart[z][q][d]) / Lsum[q].
// Works in place when obase==Out (Z==1, zstride==0).
// ---------------------------------------------------------------------------
__global__ __launch_bounds__(256) void k_reduce(
    const char* __restrict__ obase, size_t qstride, size_t zstride, int Z,
    const float* __restrict__ Lsum, float* __restrict__ Out)
{
  const int idx = blockIdx.x * 256 + threadIdx.x;
  const int q = idx >> 7;
  const int d4 = idx & 127;
  const char* p = obase + (size_t)q * qstride + (size_t)d4 * 16;
  f32x4 s = *(const f32x4*)p;
  for (int zz = 1; zz < Z; ++zz)
    s += *(const f32x4*)(p + (size_t)zz * zstride);
  float linv = 1.0f / Lsum[q];
  s *= linv;
  *(f32x4*)(Out + (size_t)q * DIM + d4 * 4) = s;
}

// ---------------------------------------------------------------------------
extern "C" void kernel_launch(void* const* d_in, const int* in_sizes, int n_in,
                              void* d_out, int out_size, void* d_ws, size_t ws_size,
                              hipStream_t stream) {
  const float* Wq = (const float*)d_in[0];
  const float* Wk = (const float*)d_in[1];
  const float* X  = (const float*)d_in[2];
  float* Out = (float*)d_out;

  char* w = (char*)d_ws;
  const size_t SPLIT  = (size_t)NSEQ * DIM * 2;          // 8 MB per f16 matrix
  const size_t XBYTES = (size_t)DIM * VPITCH * 2;        // padded XhT
  f16* Qh  = (f16*)(w);
  f16* Ql  = (f16*)(w + SPLIT);
  f16* Kh  = (f16*)(w + 2 * SPLIT);
  f16* Kl  = (f16*)(w + 3 * SPLIT);
  f16* XhT = (f16*)(w + 4 * SPLIT);
  float* Lsum = (float*)(w + 4 * SPLIT + XBYTES);
  const size_t used_base = 4 * SPLIT + XBYTES + 32768;
  char* rest = w + used_base;
  const size_t SBYTES_FULL = (size_t)NSEQ * SROWB;       // ~271 MB
  const size_t PBYTES      = (size_t)NSEQ * SPITCH * 2;  // ~135 MB (chunked)
  const size_t OPART1      = (size_t)NSEQ * DIM * 4;     // 16 MB per partial

  float* S; f16* P; int ppitch; int CQ;
  int Z; char* obase; size_t qstride, zstride;
  if (ws_size >= used_base + SBYTES_FULL) {
    // Full S (pitch SPITCH); P f16 overlays first 16 KB of each S row; the
    // dead upper part of each row holds the Z split-j partials (Z x 2 KB).
    S = (float*)rest; P = (f16*)rest; ppitch = 2 * SPITCH; CQ = NSEQ;
    Z = 4;
    obase = rest + 16384;
    qstride = SROWB;
    zstride = 2048;
  } else {
    // Separate P, chunked S. After the last softmax chunk the S region is
    // dead -> holds the split-j partials.
    P = (f16*)rest; ppitch = SPITCH;
    S = (float*)(rest + PBYTES);
    size_t avail = (ws_size > used_base + PBYTES) ? ws_size - used_base - PBYTES : 0;
    CQ = 4096;
    while (CQ > 128 && (size_t)CQ * SROWB > avail) CQ >>= 1;
    size_t schunk = (size_t)CQ * SROWB;
    Z = (int)(schunk / OPART1);
    if (Z > 4) Z = 4;
    if (Z >= 1) {
      obase = (char*)S; qstride = DIM * 4; zstride = OPART1;
    } else {
      Z = 1; obase = (char*)Out; qstride = DIM * 4; zstride = 0;
    }
  }

  const float SCALE = 0.044194173824159216f;  // 1/sqrt(512)
  k_proj_split<<<dim3(NSEQ / 64, DIM / 64), 256, 0, stream>>>(X, Wq, Qh, Ql, SCALE);
  k_proj_split<<<dim3(NSEQ / 64, DIM / 64), 256, 0, stream>>>(X, Wk, Kh, Kl, 1.0f);
  k_xt<<<dim3(NSEQ / 64, DIM / 64), 256, 0, stream>>>(X, XhT);
  for (int q0 = 0; q0 < NSEQ; q0 += CQ) {
    k_qkt<<<dim3(CQ / 128, NSEQ / 128), 256, 0, stream>>>(Qh, Ql, Kh, Kl, S, q0);
    k_softmax<<<dim3(CQ), 256, 0, stream>>>(S, P, Lsum, q0, ppitch);
  }
  k_pv2<<<dim3(NSEQ / 32, Z), 256, 0, stream>>>(XhT, P, obase, ppitch,
                                                qstride, zstride, NSEQ / Z);
  k_reduce<<<NSEQ * (DIM / 4) / 256, 256, 0, stream>>>(obase, qstride, zstride,
                                                       Z, Lsum, Out);
}